// Round 13
// baseline (1409.833 us; speedup 1.0000x reference)
//
#include <hip/hip_runtime.h>
#include <hip/hip_bf16.h>

#define N_USERS 6144
#define N_ITEMS 12288
#define N_NODES 18432
#define D 64
#define NNZ 589824
#define K_TOP 31      // K+1
#define TSEL 96       // key-top-96 guarantee (r8 safety arithmetic)
#define CAP_CAND 1024 // per-row candidate cap (expected ~150)
#define NTILES 192    // 64-col tiles per row
#define NB (N_NODES / 256)   // 72 scan blocks

using frag_ab = __attribute__((ext_vector_type(8))) short;  // 8 bf16
using frag_cd = __attribute__((ext_vector_type(4))) float;  // 4 fp32
using uint4_e = __attribute__((ext_vector_type(4))) unsigned;
using float4_e = __attribute__((ext_vector_type(4))) float;

__device__ inline unsigned f32_to_bf16_bits(float f) {
    unsigned b = __float_as_uint(f);
    return (b + 0x7FFFu + ((b >> 16) & 1u)) >> 16;          // RNE
}
__device__ inline unsigned sim_to_u8(float v) {
    float e = rintf(fmaf(v, 127.5f, 127.5f));               // [-1,1] -> [0,255]
    e = fminf(fmaxf(e, 0.f), 255.f);
    return (unsigned)(int)e;
}

// ---------------------------------------------------------------------------
// CSR build (unchanged from r12)
__global__ void count_kernel(const int* __restrict__ er, int* __restrict__ cnt) {
    int e = blockIdx.x * 256 + threadIdx.x;
    atomicAdd(&cnt[er[e]], 1);
}

__global__ __launch_bounds__(256) void scanA_kernel(const int* __restrict__ cnt,
                                                    int* __restrict__ excl,
                                                    int* __restrict__ bsum) {
    __shared__ int sh[256];
    int t = threadIdx.x, b = blockIdx.x;
    int idx = b * 256 + t;
    int v = cnt[idx];
    sh[t] = v;
    __syncthreads();
    for (int off = 1; off < 256; off <<= 1) {
        int x = sh[t];
        int y = (t >= off) ? sh[t - off] : 0;
        __syncthreads();
        sh[t] = x + y;
        __syncthreads();
    }
    excl[idx] = sh[t] - v;
    if (t == 255) bsum[b] = sh[255];
}

__global__ __launch_bounds__(256) void scanC_kernel(const int* __restrict__ excl,
                                                    const int* __restrict__ bsum,
                                                    int* __restrict__ row_start,
                                                    int* __restrict__ cursor) {
    __shared__ int sb[NB];
    int t = threadIdx.x;
    if (t < NB) sb[t] = bsum[t];
    __syncthreads();
    if (t == 0) {
        int acc = 0;
        for (int i = 0; i < NB; ++i) { int v = sb[i]; sb[i] = acc; acc += v; }
    }
    __syncthreads();
    int idx = blockIdx.x * 256 + t;
    int v = excl[idx] + sb[idx >> 8];
    row_start[idx] = v;
    cursor[idx] = v;
    if (idx == 0) row_start[N_NODES] = NNZ;
}

__global__ void scatter_kernel(const int* __restrict__ er, const int* __restrict__ ec,
                               const float* __restrict__ ev,
                               int* __restrict__ cursor, int2* __restrict__ ep) {
    int e = blockIdx.x * 256 + threadIdx.x;
    int r = er[e];
    int pos = atomicAdd(&cursor[r], 1);
    ep[pos] = make_int2(ec[e], __float_as_int(ev[e]));
}

// ---------------------------------------------------------------------------
// CSR SpMM layer 1 (unchanged from r12)
__global__ __launch_bounds__(256) void spmm_csr_kernel(const int* __restrict__ row_start,
                                                       const int2* __restrict__ ep,
                                                       const float* __restrict__ uemb,
                                                       const float* __restrict__ iemb,
                                                       double* __restrict__ y) {
    int t = threadIdx.x;
    int lane = t & 63, wave = t >> 6;
    int row = blockIdx.x * 4 + wave;
    int beg = row_start[row], end = row_start[row + 1];
    double a0 = 0.0, a1 = 0.0, a2 = 0.0, a3 = 0.0;
    int j = beg;
    int n4 = beg + ((end - beg) & ~3);
    const float* ishift = iemb - (size_t)N_USERS * D;
    for (; j < n4; j += 4) {
        int2 p0 = ep[j], p1 = ep[j + 1], p2 = ep[j + 2], p3 = ep[j + 3];
        const float* x0 = (p0.x < N_USERS) ? uemb : ishift;
        const float* x1 = (p1.x < N_USERS) ? uemb : ishift;
        const float* x2 = (p2.x < N_USERS) ? uemb : ishift;
        const float* x3 = (p3.x < N_USERS) ? uemb : ishift;
        a0 += (double)__int_as_float(p0.y) * (double)x0[(size_t)p0.x * D + lane];
        a1 += (double)__int_as_float(p1.y) * (double)x1[(size_t)p1.x * D + lane];
        a2 += (double)__int_as_float(p2.y) * (double)x2[(size_t)p2.x * D + lane];
        a3 += (double)__int_as_float(p3.y) * (double)x3[(size_t)p3.x * D + lane];
    }
    for (; j < end; ++j) {
        int2 p = ep[j];
        const float* x0 = (p.x < N_USERS) ? uemb : ishift;
        a0 += (double)__int_as_float(p.y) * (double)x0[(size_t)p.x * D + lane];
    }
    y[(size_t)row * D + lane] = (a0 + a1) + (a2 + a3);
}

// ---------------------------------------------------------------------------
// Fused: SpMM layer 2 (ITEM rows only) + mean + L2 normalize (unchanged)
__global__ __launch_bounds__(256) void spmm_norm_kernel(const int* __restrict__ row_start,
                                                        const int2* __restrict__ ep,
                                                        const float* __restrict__ iemb,
                                                        const double* __restrict__ e1,
                                                        double* __restrict__ xn64,
                                                        ushort* __restrict__ xh) {
    int t = threadIdx.x;
    int lane = t & 63, wave = t >> 6;
    int ir = blockIdx.x * 4 + wave;
    int row = ir + N_USERS;
    int beg = row_start[row], end = row_start[row + 1];
    double a0 = 0.0, a1 = 0.0, a2 = 0.0, a3 = 0.0;
    int j = beg;
    int n4 = beg + ((end - beg) & ~3);
    for (; j < n4; j += 4) {
        int2 p0 = ep[j], p1 = ep[j + 1], p2 = ep[j + 2], p3 = ep[j + 3];
        a0 += (double)__int_as_float(p0.y) * e1[(size_t)p0.x * D + lane];
        a1 += (double)__int_as_float(p1.y) * e1[(size_t)p1.x * D + lane];
        a2 += (double)__int_as_float(p2.y) * e1[(size_t)p2.x * D + lane];
        a3 += (double)__int_as_float(p3.y) * e1[(size_t)p3.x * D + lane];
    }
    for (; j < end; ++j) {
        int2 p = ep[j];
        a0 += (double)__int_as_float(p.y) * e1[(size_t)p.x * D + lane];
    }
    double e2v = (a0 + a1) + (a2 + a3);

    double e0v = (double)iemb[(size_t)ir * D + lane];
    double s = (e0v + e1[(size_t)row * D + lane] + e2v) / 3.0;
    double ss = s * s;
    #pragma unroll
    for (int off = 32; off; off >>= 1) ss += __shfl_xor(ss, off);
    double norm = sqrt(ss);
    double denom = fmax(norm, 1e-12);
    double v = s / denom;
    xn64[(size_t)ir * D + lane] = v;
    xh[(size_t)ir * D + lane] = (ushort)f32_to_bf16_bits((float)v);
}

// ---------------------------------------------------------------------------
// Shared GEMM core pieces (128x128 tile, bi<=bj triangular, 16x16x32 MFMA)
#define LDS_STRIDE 72    // staging stride (shorts); 2-way bank conflict (free)

// Phase 1: per-(row, 64-col-tile) u8 maxima of both images, via wave shuffles.
__global__ __launch_bounds__(256) void gemm_rowmax_kernel(const ushort* __restrict__ Xh,
                                                          unsigned char* __restrict__ rowmax) {
    __shared__ __align__(16) ushort S[2 * 128 * LDS_STRIDE];
    int bi = blockIdx.y, bj = blockIdx.x;
    if (bj < bi) return;
    ushort* Als = S;
    ushort* Bls = S + 128 * LDS_STRIDE;
    int t = threadIdx.x;

    #pragma unroll
    for (int p = 0; p < 4; ++p) {
        int u4 = t + 256 * p;
        int row = u4 >> 3;
        int seg = u4 & 7;
        *(uint4_e*)&Als[row * LDS_STRIDE + seg * 8] =
            *(const uint4_e*)&Xh[(size_t)(bi * 128 + row) * D + seg * 8];
        *(uint4_e*)&Bls[row * LDS_STRIDE + seg * 8] =
            *(const uint4_e*)&Xh[(size_t)(bj * 128 + row) * D + seg * 8];
    }
    __syncthreads();

    int lane = t & 63, wave = t >> 6;
    int wrow = (wave >> 1) * 64, wcol = (wave & 1) * 64;
    int ml = lane & 15, quad = lane >> 4;

    frag_cd acc[4][4] = {};
    #pragma unroll
    for (int s = 0; s < 2; ++s) {
        frag_ab af[4], bf[4];
        int koff = s * 32 + quad * 8;
        #pragma unroll
        for (int rt = 0; rt < 4; ++rt)
            af[rt] = *(const frag_ab*)&Als[(wrow + rt * 16 + ml) * LDS_STRIDE + koff];
        #pragma unroll
        for (int ct = 0; ct < 4; ++ct)
            bf[ct] = *(const frag_ab*)&Bls[(wcol + ct * 16 + ml) * LDS_STRIDE + koff];
        #pragma unroll
        for (int rt = 0; rt < 4; ++rt)
            #pragma unroll
            for (int ct = 0; ct < 4; ++ct)
                acc[rt][ct] = __builtin_amdgcn_mfma_f32_16x16x32_bf16(
                    af[rt], bf[ct], acc[rt][ct], 0, 0, 0);
    }

    // image-1: per-row max over this wave's 64 cols (one 64-col tile)
    unsigned m1[4][4];                   // [rt][reg]
    #pragma unroll
    for (int rt = 0; rt < 4; ++rt)
        #pragma unroll
        for (int r = 0; r < 4; ++r) {
            unsigned q = sim_to_u8(acc[rt][0][r]);
            #pragma unroll
            for (int ct = 1; ct < 4; ++ct) {
                unsigned q2 = sim_to_u8(acc[rt][ct][r]);
                if (q2 > q) q = q2;
            }
            m1[rt][r] = q;
        }
    #pragma unroll
    for (int mask = 1; mask <= 8; mask <<= 1)
        #pragma unroll
        for (int rt = 0; rt < 4; ++rt)
            #pragma unroll
            for (int r = 0; r < 4; ++r) {
                unsigned o = (unsigned)__shfl_xor((int)m1[rt][r], mask);
                if (o > m1[rt][r]) m1[rt][r] = o;
            }
    if (ml == 0) {
        int tidx = bj * 2 + (wcol >> 6);
        #pragma unroll
        for (int rt = 0; rt < 4; ++rt)
            #pragma unroll
            for (int r = 0; r < 4; ++r)
                rowmax[(size_t)(bi * 128 + wrow + rt * 16 + quad * 4 + r) * NTILES + tidx] =
                    (unsigned char)m1[rt][r];
    }

    // image-2 (transpose): per-col max over this wave's 64 rows
    if (bi != bj) {
        unsigned m2[4];                  // [ct]
        #pragma unroll
        for (int ct = 0; ct < 4; ++ct) {
            unsigned q = 0;
            #pragma unroll
            for (int rt = 0; rt < 4; ++rt)
                #pragma unroll
                for (int r = 0; r < 4; ++r) {
                    unsigned q2 = sim_to_u8(acc[rt][ct][r]);
                    if (q2 > q) q = q2;
                }
            m2[ct] = q;
        }
        #pragma unroll
        for (int mask = 16; mask <= 32; mask <<= 1)
            #pragma unroll
            for (int ct = 0; ct < 4; ++ct) {
                unsigned o = (unsigned)__shfl_xor((int)m2[ct], mask);
                if (o > m2[ct]) m2[ct] = o;
            }
        if (quad == 0) {
            int tidx = bi * 2 + (wrow >> 6);
            #pragma unroll
            for (int ct = 0; ct < 4; ++ct)
                rowmax[(size_t)(bj * 128 + wcol + ct * 16 + ml) * NTILES + tidx] =
                    (unsigned char)m2[ct];
        }
    }
}

// ---------------------------------------------------------------------------
// Per-row threshold: T = max{q : #(tilemax >= q) >= TSEL}.  Wave per row.
__global__ __launch_bounds__(256) void rowthresh_kernel(const unsigned char* __restrict__ rowmax,
                                                        unsigned char* __restrict__ Trow) {
    int t = threadIdx.x;
    int lane = t & 63;
    int row = blockIdx.x * 4 + (t >> 6);
    const unsigned char* rm = rowmax + (size_t)row * NTILES;
    int a = rm[lane], b = rm[lane + 64], c = rm[lane + 128];
    int lo = 0, hi = 255;
    #pragma unroll
    for (int it = 0; it < 8; ++it) {
        int mid = (lo + hi + 1) >> 1;
        int cc = (a >= mid) + (b >= mid) + (c >= mid);
        #pragma unroll
        for (int off = 32; off; off >>= 1) cc += __shfl_xor(cc, off);
        if (cc >= TSEL) lo = mid; else hi = mid - 1;
    }
    if (lane == 0) Trow[row] = (unsigned char)lo;
}

// ---------------------------------------------------------------------------
// Phase 2: GEMM again; append packed (key<<16 | col) for keys >= T[row],
// both images, into per-row global buckets (cap CAP_CAND; counter exact).
__global__ __launch_bounds__(256) void gemm_emit_kernel(const ushort* __restrict__ Xh,
                                                        const unsigned char* __restrict__ Trow,
                                                        int* __restrict__ ccnt,
                                                        unsigned* __restrict__ candbuf) {
    __shared__ __align__(16) ushort S[2 * 128 * LDS_STRIDE];
    __shared__ unsigned char sTrow[128], sTcol[128];
    int bi = blockIdx.y, bj = blockIdx.x;
    if (bj < bi) return;
    ushort* Als = S;
    ushort* Bls = S + 128 * LDS_STRIDE;
    int t = threadIdx.x;

    if (t < 128) {
        sTrow[t] = Trow[bi * 128 + t];
        sTcol[t] = Trow[bj * 128 + t];
    }
    #pragma unroll
    for (int p = 0; p < 4; ++p) {
        int u4 = t + 256 * p;
        int row = u4 >> 3;
        int seg = u4 & 7;
        *(uint4_e*)&Als[row * LDS_STRIDE + seg * 8] =
            *(const uint4_e*)&Xh[(size_t)(bi * 128 + row) * D + seg * 8];
        *(uint4_e*)&Bls[row * LDS_STRIDE + seg * 8] =
            *(const uint4_e*)&Xh[(size_t)(bj * 128 + row) * D + seg * 8];
    }
    __syncthreads();

    int lane = t & 63, wave = t >> 6;
    int wrow = (wave >> 1) * 64, wcol = (wave & 1) * 64;
    int ml = lane & 15, quad = lane >> 4;

    frag_cd acc[4][4] = {};
    #pragma unroll
    for (int s = 0; s < 2; ++s) {
        frag_ab af[4], bf[4];
        int koff = s * 32 + quad * 8;
        #pragma unroll
        for (int rt = 0; rt < 4; ++rt)
            af[rt] = *(const frag_ab*)&Als[(wrow + rt * 16 + ml) * LDS_STRIDE + koff];
        #pragma unroll
        for (int ct = 0; ct < 4; ++ct)
            bf[ct] = *(const frag_ab*)&Bls[(wcol + ct * 16 + ml) * LDS_STRIDE + koff];
        #pragma unroll
        for (int rt = 0; rt < 4; ++rt)
            #pragma unroll
            for (int ct = 0; ct < 4; ++ct)
                acc[rt][ct] = __builtin_amdgcn_mfma_f32_16x16x32_bf16(
                    af[rt], bf[ct], acc[rt][ct], 0, 0, 0);
    }

    int offdiag = (bi != bj);
    #pragma unroll
    for (int rt = 0; rt < 4; ++rt) {
        #pragma unroll
        for (int ct = 0; ct < 4; ++ct) {
            #pragma unroll
            for (int r = 0; r < 4; ++r) {
                unsigned q = sim_to_u8(acc[rt][ct][r]);
                int row1 = wrow + rt * 16 + quad * 4 + r;
                int col1 = wcol + ct * 16 + ml;
                if (q >= (unsigned)sTrow[row1]) {
                    int g = bi * 128 + row1;
                    int pos = atomicAdd(&ccnt[g], 1);
                    if (pos < CAP_CAND)
                        candbuf[(size_t)g * CAP_CAND + pos] = (q << 16) | (unsigned)(bj * 128 + col1);
                }
                if (offdiag && q >= (unsigned)sTcol[col1]) {
                    int g = bj * 128 + col1;
                    int pos = atomicAdd(&ccnt[g], 1);
                    if (pos < CAP_CAND)
                        candbuf[(size_t)g * CAP_CAND + pos] = (q << 16) | (unsigned)(bi * 128 + row1);
                }
            }
        }
    }
}

// ---------------------------------------------------------------------------
// Finalize per row: re-bisect candidate keys to the exact 96-count threshold,
// fp64-recompute survivors, rank-by-count top-31, zero + scatter.
// Fallback (cnt > CAP_CAND, expected never): full fp64 row recompute.
__global__ __launch_bounds__(256) void finalize_kernel(const int* __restrict__ ccnt,
                                                       const unsigned* __restrict__ candbuf,
                                                       const double* __restrict__ xn64,
                                                       float* __restrict__ Cout) {
    __shared__ int      candi[CAP_CAND];     // packed key<<16 | col
    __shared__ double   candv[CAP_CAND];
    __shared__ double   s_xr[D];
    __shared__ int s_red[4];
    __shared__ unsigned s_cnt;
    int t = threadIdx.x;
    int r = blockIdx.x;
    if (t < D) s_xr[t] = xn64[(size_t)r * D + t];
    int cval = ccnt[r];
    int c;

    if (cval <= CAP_CAND) {
        for (int i = t; i < cval; i += 256) candi[i] = (int)candbuf[(size_t)r * CAP_CAND + i];
        c = cval;
        __syncthreads();
        // bisect candidate keys for T' = max{q : count(key>=q) >= TSEL}
        int lo = 0, hi = 255;
        for (int it = 0; it < 8; ++it) {
            int mid = (lo + hi + 1) >> 1;
            int cc = 0;
            for (int i = t; i < c; i += 256) cc += ((candi[i] >> 16) >= mid);
            #pragma unroll
            for (int off = 32; off; off >>= 1) cc += __shfl_down(cc, off);
            if ((t & 63) == 0) s_red[t >> 6] = cc;
            __syncthreads();
            int ctot = s_red[0] + s_red[1] + s_red[2] + s_red[3];
            __syncthreads();
            if (ctot >= TSEL) lo = mid; else hi = mid - 1;
        }
        int Tp = lo;
        // fp64 recompute only survivors; prune the rest to -inf
        for (int i = t; i < c; i += 256) {
            if ((candi[i] >> 16) >= Tp) {
                const double* xc = xn64 + (size_t)(candi[i] & 0xFFFF) * D;
                double a = 0.0;
                #pragma unroll 8
                for (int k = 0; k < D; ++k) a += s_xr[k] * xc[k];
                candv[i] = a;
            } else {
                candv[i] = -1.0e300;
            }
        }
        __syncthreads();
    } else {
        // fallback: full-row fp64 recompute + bisect + threshold-append
        __syncthreads();                 // s_xr visible
        unsigned char u[48];
        #pragma unroll
        for (int j = 0; j < 48; ++j) {
            int col = t + 256 * j;
            const double* xc = xn64 + (size_t)col * D;
            double a = 0.0;
            #pragma unroll 8
            for (int k = 0; k < D; ++k) a += s_xr[k] * xc[k];
            u[j] = (unsigned char)sim_to_u8((float)a);
        }
        int lo = 0, hi = 255;
        for (int it = 0; it < 8; ++it) {
            int mid = (lo + hi + 1) >> 1;
            int cc = 0;
            #pragma unroll
            for (int j = 0; j < 48; ++j) cc += ((int)u[j] >= mid);
            #pragma unroll
            for (int off = 32; off; off >>= 1) cc += __shfl_down(cc, off);
            if ((t & 63) == 0) s_red[t >> 6] = cc;
            __syncthreads();
            int ctot = s_red[0] + s_red[1] + s_red[2] + s_red[3];
            __syncthreads();
            if (ctot >= TSEL) lo = mid; else hi = mid - 1;
        }
        int T2 = lo;
        if (t == 0) s_cnt = 0;
        __syncthreads();
        #pragma unroll
        for (int j = 0; j < 48; ++j) {
            if ((int)u[j] >= T2) {
                int col = t + 256 * j;
                const double* xc = xn64 + (size_t)col * D;
                double a = 0.0;
                #pragma unroll 8
                for (int k = 0; k < D; ++k) a += s_xr[k] * xc[k];
                unsigned pos = atomicAdd(&s_cnt, 1u);
                if (pos < CAP_CAND) {
                    candi[pos] = ((int)u[j] << 16) | col;
                    candv[pos] = a;
                }
            }
        }
        __syncthreads();
        c = (int)s_cnt; if (c > CAP_CAND) c = CAP_CAND;
    }

    // rank-by-count: exact fp64 top-31, ties -> lower col index
    int   sel_col[4];
    float sel_val[4];
    int nsel = 0;
    for (int i = t; i < c; i += 256) {
        double v = candv[i];
        int col_i = candi[i] & 0xFFFF;
        int rank = 0;
        for (int j = 0; j < c; ++j) {
            double vj = candv[j];
            int cj = candi[j] & 0xFFFF;
            rank += (vj > v || (vj == v && cj < col_i)) ? 1 : 0;
        }
        if (rank < K_TOP) {
            sel_col[nsel] = col_i;
            sel_val[nsel] = (v > 0.0) ? (float)v : 0.f;
            ++nsel;
        }
    }

    // write zeros (nontemporal), then scatter selected (barrier orders WAW)
    float4_e* Orow4 = (float4_e*)(Cout + (size_t)r * N_ITEMS);
    float4_e z = {0.f, 0.f, 0.f, 0.f};
    #pragma unroll
    for (int j = 0; j < 12; ++j)
        __builtin_nontemporal_store(z, &Orow4[t + 256 * j]);
    __syncthreads();
    for (int s = 0; s < nsel; ++s)
        Cout[(size_t)r * N_ITEMS + sel_col[s]] = sel_val[s];
}

// ---------------------------------------------------------------------------
extern "C" void kernel_launch(void* const* d_in, const int* in_sizes, int n_in,
                              void* d_out, int out_size, void* d_ws, size_t ws_size,
                              hipStream_t stream) {
    const float* user_emb = (const float*)d_in[0];
    const float* item_emb = (const float*)d_in[1];
    const int*   edge_row = (const int*)d_in[2];
    const int*   edge_col = (const int*)d_in[3];
    const float* edge_val = (const float*)d_in[4];
    float* C = (float*)d_out;

    double* e1d  = (double*)d_ws;                         // N_NODES*D f64
    double* xn64 = e1d + (size_t)N_NODES * D;             // N_ITEMS*D f64
    int2*   ep   = (int2*)(xn64 + (size_t)N_ITEMS * D);   // NNZ int2
    unsigned* candbuf = (unsigned*)(ep + NNZ);            // N_ITEMS*CAP_CAND u32
    int*  cnt       = (int*)(candbuf + (size_t)N_ITEMS * CAP_CAND);  // N_NODES
    int*  ccnt      = cnt + N_NODES;                      // N_ITEMS (adjacent: one memset)
    int*  excl      = ccnt + N_ITEMS;
    int*  row_start = excl + N_NODES;
    int*  cursor    = row_start + N_NODES + 1;
    int*  bsum      = cursor + N_NODES;                   // NB (pad 128)
    ushort* xh      = (ushort*)(bsum + 128);              // N_ITEMS*D bf16
    unsigned char* rowmax = (unsigned char*)(xh + (size_t)N_ITEMS * D);  // N_ITEMS*NTILES
    unsigned char* Trow   = rowmax + (size_t)N_ITEMS * NTILES;           // N_ITEMS

    (void)hipMemsetAsync(cnt, 0, (N_NODES + N_ITEMS) * sizeof(int), stream);

    count_kernel<<<NNZ / 256, 256, 0, stream>>>(edge_row, cnt);
    scanA_kernel<<<N_NODES / 256, 256, 0, stream>>>(cnt, excl, bsum);
    scanC_kernel<<<N_NODES / 256, 256, 0, stream>>>(excl, bsum, row_start, cursor);
    scatter_kernel<<<NNZ / 256, 256, 0, stream>>>(edge_row, edge_col, edge_val, cursor, ep);

    spmm_csr_kernel<<<N_NODES / 4, 256, 0, stream>>>(row_start, ep, user_emb, item_emb, e1d);
    spmm_norm_kernel<<<N_ITEMS / 4, 256, 0, stream>>>(row_start, ep, item_emb, e1d, xn64, xh);

    dim3 ggrid(N_ITEMS / 128, N_ITEMS / 128);
    gemm_rowmax_kernel<<<ggrid, 256, 0, stream>>>(xh, rowmax);
    rowthresh_kernel<<<N_ITEMS / 4, 256, 0, stream>>>(rowmax, Trow);
    gemm_emit_kernel<<<ggrid, 256, 0, stream>>>(xh, Trow, ccnt, candbuf);

    finalize_kernel<<<N_ITEMS, 256, 0, stream>>>(ccnt, candbuf, xn64, C);
}

// Round 14
// 890.132 us; speedup vs baseline: 1.5838x; 1.5838x over previous
//
#include <hip/hip_runtime.h>
#include <hip/hip_bf16.h>

#define N_USERS 6144
#define N_ITEMS 12288
#define N_NODES 18432
#define D 64
#define NNZ 589824
#define K_TOP 31     // K+1
#define NCAND_MIN 96 // u8 preselect margin over 31 (r8 safety arithmetic)
#define CMAX 256
#define NB (N_NODES / 256)   // 72 scan blocks

using frag_ab = __attribute__((ext_vector_type(8))) short;  // 8 bf16
using frag_cd = __attribute__((ext_vector_type(4))) float;  // 4 fp32
using uint4_e = __attribute__((ext_vector_type(4))) unsigned;
using uint2_e = __attribute__((ext_vector_type(2))) unsigned;
using float4_e = __attribute__((ext_vector_type(4))) float;

__device__ inline unsigned f32_to_bf16_bits(float f) {
    unsigned b = __float_as_uint(f);
    return (b + 0x7FFFu + ((b >> 16) & 1u)) >> 16;          // RNE
}
__device__ inline unsigned sim_to_u8(float v) {
    float e = rintf(fmaf(v, 127.5f, 127.5f));               // [-1,1] -> [0,255]
    e = fminf(fmaxf(e, 0.f), 255.f);
    return (unsigned)(int)e;
}

// ---------------------------------------------------------------------------
// CSR build: count, scanA (per-256 local), scanC (merged block-sum scan),
// scatter (packed int2 {col, val_bits})
__global__ void count_kernel(const int* __restrict__ er, int* __restrict__ cnt) {
    int e = blockIdx.x * 256 + threadIdx.x;
    atomicAdd(&cnt[er[e]], 1);
}

__global__ __launch_bounds__(256) void scanA_kernel(const int* __restrict__ cnt,
                                                    int* __restrict__ excl,
                                                    int* __restrict__ bsum) {
    __shared__ int sh[256];
    int t = threadIdx.x, b = blockIdx.x;
    int idx = b * 256 + t;
    int v = cnt[idx];
    sh[t] = v;
    __syncthreads();
    for (int off = 1; off < 256; off <<= 1) {
        int x = sh[t];
        int y = (t >= off) ? sh[t - off] : 0;
        __syncthreads();
        sh[t] = x + y;
        __syncthreads();
    }
    excl[idx] = sh[t] - v;
    if (t == 255) bsum[b] = sh[255];
}

__global__ __launch_bounds__(256) void scanC_kernel(const int* __restrict__ excl,
                                                    const int* __restrict__ bsum,
                                                    int* __restrict__ row_start,
                                                    int* __restrict__ cursor) {
    __shared__ int sb[NB];
    int t = threadIdx.x;
    if (t < NB) sb[t] = bsum[t];
    __syncthreads();
    if (t == 0) {
        int acc = 0;
        for (int i = 0; i < NB; ++i) { int v = sb[i]; sb[i] = acc; acc += v; }
    }
    __syncthreads();
    int idx = blockIdx.x * 256 + t;
    int v = excl[idx] + sb[idx >> 8];
    row_start[idx] = v;
    cursor[idx] = v;
    if (idx == 0) row_start[N_NODES] = NNZ;
}

__global__ void scatter_kernel(const int* __restrict__ er, const int* __restrict__ ec,
                               const float* __restrict__ ev,
                               int* __restrict__ cursor, int2* __restrict__ ep) {
    int e = blockIdx.x * 256 + threadIdx.x;
    int r = er[e];
    int pos = atomicAdd(&cursor[r], 1);
    ep[pos] = make_int2(ec[e], __float_as_int(ev[e]));
}

// ---------------------------------------------------------------------------
// CSR SpMM layer 1 (all rows), fp64 accumulate, gathers DIRECTLY from the
// fp32 inputs (bit-identical to promoting into a concat'd fp64 e0).
__global__ __launch_bounds__(256) void spmm_csr_kernel(const int* __restrict__ row_start,
                                                       const int2* __restrict__ ep,
                                                       const float* __restrict__ uemb,
                                                       const float* __restrict__ iemb,
                                                       double* __restrict__ y) {
    int t = threadIdx.x;
    int lane = t & 63, wave = t >> 6;
    int row = blockIdx.x * 4 + wave;
    int beg = row_start[row], end = row_start[row + 1];
    double a0 = 0.0, a1 = 0.0, a2 = 0.0, a3 = 0.0;
    int j = beg;
    int n4 = beg + ((end - beg) & ~3);
    const float* ishift = iemb - (size_t)N_USERS * D;      // index with global col
    for (; j < n4; j += 4) {
        int2 p0 = ep[j], p1 = ep[j + 1], p2 = ep[j + 2], p3 = ep[j + 3];
        const float* x0 = (p0.x < N_USERS) ? uemb : ishift;
        const float* x1 = (p1.x < N_USERS) ? uemb : ishift;
        const float* x2 = (p2.x < N_USERS) ? uemb : ishift;
        const float* x3 = (p3.x < N_USERS) ? uemb : ishift;
        a0 += (double)__int_as_float(p0.y) * (double)x0[(size_t)p0.x * D + lane];
        a1 += (double)__int_as_float(p1.y) * (double)x1[(size_t)p1.x * D + lane];
        a2 += (double)__int_as_float(p2.y) * (double)x2[(size_t)p2.x * D + lane];
        a3 += (double)__int_as_float(p3.y) * (double)x3[(size_t)p3.x * D + lane];
    }
    for (; j < end; ++j) {
        int2 p = ep[j];
        const float* x0 = (p.x < N_USERS) ? uemb : ishift;
        a0 += (double)__int_as_float(p.y) * (double)x0[(size_t)p.x * D + lane];
    }
    y[(size_t)row * D + lane] = (a0 + a1) + (a2 + a3);
}

// ---------------------------------------------------------------------------
// Fused: SpMM layer 2 (ITEM rows only) + mean(e0,e1,e2) + L2 normalize.
__global__ __launch_bounds__(256) void spmm_norm_kernel(const int* __restrict__ row_start,
                                                        const int2* __restrict__ ep,
                                                        const float* __restrict__ iemb,
                                                        const double* __restrict__ e1,
                                                        double* __restrict__ xn64,
                                                        ushort* __restrict__ xh) {
    int t = threadIdx.x;
    int lane = t & 63, wave = t >> 6;
    int ir = blockIdx.x * 4 + wave;                  // item index
    int row = ir + N_USERS;
    int beg = row_start[row], end = row_start[row + 1];
    double a0 = 0.0, a1 = 0.0, a2 = 0.0, a3 = 0.0;
    int j = beg;
    int n4 = beg + ((end - beg) & ~3);
    for (; j < n4; j += 4) {
        int2 p0 = ep[j], p1 = ep[j + 1], p2 = ep[j + 2], p3 = ep[j + 3];
        a0 += (double)__int_as_float(p0.y) * e1[(size_t)p0.x * D + lane];
        a1 += (double)__int_as_float(p1.y) * e1[(size_t)p1.x * D + lane];
        a2 += (double)__int_as_float(p2.y) * e1[(size_t)p2.x * D + lane];
        a3 += (double)__int_as_float(p3.y) * e1[(size_t)p3.x * D + lane];
    }
    for (; j < end; ++j) {
        int2 p = ep[j];
        a0 += (double)__int_as_float(p.y) * e1[(size_t)p.x * D + lane];
    }
    double e2v = (a0 + a1) + (a2 + a3);

    double e0v = (double)iemb[(size_t)ir * D + lane];
    double s = (e0v + e1[(size_t)row * D + lane] + e2v) / 3.0;
    double ss = s * s;
    #pragma unroll
    for (int off = 32; off; off >>= 1) ss += __shfl_xor(ss, off);
    double norm = sqrt(ss);
    double denom = fmax(norm, 1e-12);
    double v = s / denom;
    xn64[(size_t)ir * D + lane] = v;
    xh[(size_t)ir * D + lane] = (ushort)f32_to_bf16_bits((float)v);
}

// ---------------------------------------------------------------------------
// Cu8 = u8(Xh * Xh^T), symmetric: only bi<=bj computed; transposed image is
// written as PACKED u32 (4 consecutive rows per lane = 4 consecutive bytes).
#define LDS_STRIDE 72    // staging stride (shorts); 2-way bank conflict (free)
#define OST_STRIDE 136   // epilogue stride (bytes); 8 B aligned, 2-way max
__global__ __launch_bounds__(256) void simgemm_kernel(const ushort* __restrict__ Xh,
                                                      unsigned char* __restrict__ Cu8) {
    __shared__ __align__(16) ushort S[2 * 128 * LDS_STRIDE];   // 36 KB
    int bi = blockIdx.y, bj = blockIdx.x;
    if (bj < bi) return;                             // lower triangle: dead block
    ushort* Als = S;
    ushort* Bls = S + 128 * LDS_STRIDE;
    int t = threadIdx.x;

    #pragma unroll
    for (int p = 0; p < 4; ++p) {
        int u4 = t + 256 * p;            // 0..1023
        int row = u4 >> 3;               // 8 uint4 per 64-short row
        int seg = u4 & 7;
        *(uint4_e*)&Als[row * LDS_STRIDE + seg * 8] =
            *(const uint4_e*)&Xh[(size_t)(bi * 128 + row) * D + seg * 8];
        *(uint4_e*)&Bls[row * LDS_STRIDE + seg * 8] =
            *(const uint4_e*)&Xh[(size_t)(bj * 128 + row) * D + seg * 8];
    }
    __syncthreads();

    int lane = t & 63, wave = t >> 6;
    int wrow = (wave >> 1) * 64, wcol = (wave & 1) * 64;
    int ml = lane & 15, quad = lane >> 4;

    frag_cd acc[4][4] = {};
    #pragma unroll
    for (int s = 0; s < 2; ++s) {
        frag_ab af[4], bf[4];
        int koff = s * 32 + quad * 8;
        #pragma unroll
        for (int rt = 0; rt < 4; ++rt)
            af[rt] = *(const frag_ab*)&Als[(wrow + rt * 16 + ml) * LDS_STRIDE + koff];
        #pragma unroll
        for (int ct = 0; ct < 4; ++ct)
            bf[ct] = *(const frag_ab*)&Bls[(wcol + ct * 16 + ml) * LDS_STRIDE + koff];
        #pragma unroll
        for (int rt = 0; rt < 4; ++rt)
            #pragma unroll
            for (int ct = 0; ct < 4; ++ct)
                acc[rt][ct] = __builtin_amdgcn_mfma_f32_16x16x32_bf16(
                    af[rt], bf[ct], acc[rt][ct], 0, 0, 0);
    }
    __syncthreads();                     // all LDS reads consumed

    // acc -> u8 -> image1 [row][col] (b8 writes) + image2 [col][row] (packed b32)
    unsigned char* Ost  = (unsigned char*)S;                    // 17408 B
    unsigned char* Ost2 = (unsigned char*)S + 128 * OST_STRIDE; // 34816 <= 36864
    int offdiag = (bi != bj);
    #pragma unroll
    for (int rt = 0; rt < 4; ++rt) {
        #pragma unroll
        for (int ct = 0; ct < 4; ++ct) {
            int row = wrow + rt * 16 + quad * 4;     // row % 4 == 0
            int col = wcol + ct * 16 + ml;
            unsigned q0 = sim_to_u8(acc[rt][ct][0]);
            unsigned q1 = sim_to_u8(acc[rt][ct][1]);
            unsigned q2 = sim_to_u8(acc[rt][ct][2]);
            unsigned q3 = sim_to_u8(acc[rt][ct][3]);
            Ost[(row + 0) * OST_STRIDE + col] = (unsigned char)q0;
            Ost[(row + 1) * OST_STRIDE + col] = (unsigned char)q1;
            Ost[(row + 2) * OST_STRIDE + col] = (unsigned char)q2;
            Ost[(row + 3) * OST_STRIDE + col] = (unsigned char)q3;
            if (offdiag)
                *(unsigned*)&Ost2[col * OST_STRIDE + row] =
                    q0 | (q1 << 8) | (q2 << 16) | (q3 << 24);
        }
    }
    __syncthreads();

    // coalesced nontemporal stores: 2048 uint2 per image
    const size_t base1 = (size_t)(bi * 128) * N_ITEMS + bj * 128;
    #pragma unroll
    for (int p = 0; p < 8; ++p) {
        int i = t + 256 * p;             // 0..2047
        int row = i >> 4, seg = i & 15;
        uint2_e v = *(const uint2_e*)&Ost[row * OST_STRIDE + seg * 8];
        __builtin_nontemporal_store(v, (uint2_e*)(Cu8 + base1 + (size_t)row * N_ITEMS + seg * 8));
    }
    if (offdiag) {
        const size_t base2 = (size_t)(bj * 128) * N_ITEMS + bi * 128;
        #pragma unroll
        for (int p = 0; p < 8; ++p) {
            int i = t + 256 * p;
            int row = i >> 4, seg = i & 15;
            uint2_e v = *(const uint2_e*)&Ost2[row * OST_STRIDE + seg * 8];
            __builtin_nontemporal_store(v, (uint2_e*)(Cu8 + base2 + (size_t)row * N_ITEMS + seg * 8));
        }
    }
}

// ---------------------------------------------------------------------------
// Per-row top-31 from u8 sim: 8-round bisection preselect (register-resident),
// fp64 recompute of <=CMAX candidates, rank-by-count selection.
__global__ __launch_bounds__(256) void topk_kernel(const unsigned char* __restrict__ Cu8,
                                                   float* __restrict__ Cout,
                                                   const double* __restrict__ xn64) {
    __shared__ int s_red[4];
    __shared__ unsigned s_cnt;
    __shared__ int    candi[CMAX];
    __shared__ double candv[CMAX];
    __shared__ double s_xr[D];
    int t = threadIdx.x;
    int r = blockIdx.x;
    const uint4_e* Crow4 = (const uint4_e*)(Cu8 + (size_t)r * N_ITEMS);  // 768 uint4

    unsigned char u[48];
    #pragma unroll
    for (int j = 0; j < 3; ++j) {
        uint4_e f = __builtin_nontemporal_load(&Crow4[t + 256 * j]);
        #pragma unroll
        for (int q = 0; q < 4; ++q) {
            unsigned w = f[q];
            u[j * 16 + q * 4 + 0] = (unsigned char)(w & 0xFF);
            u[j * 16 + q * 4 + 1] = (unsigned char)((w >> 8) & 0xFF);
            u[j * 16 + q * 4 + 2] = (unsigned char)((w >> 16) & 0xFF);
            u[j * 16 + q * 4 + 3] = (unsigned char)(w >> 24);
        }
    }
    if (t < D) s_xr[t] = xn64[(size_t)r * D + t];

    // largest T in [0,255] with count(u >= T) >= NCAND_MIN  (8 fixed rounds)
    int lo = 0, hi = 255;
    #pragma unroll
    for (int it = 0; it < 8; ++it) {
        int mid = (lo + hi + 1) >> 1;
        int c = 0;
        #pragma unroll
        for (int k = 0; k < 48; ++k) c += ((int)u[k] >= mid) ? 1 : 0;
        #pragma unroll
        for (int off = 32; off; off >>= 1) c += __shfl_down(c, off);
        if ((t & 63) == 0) s_red[t >> 6] = c;
        __syncthreads();
        int ctot = s_red[0] + s_red[1] + s_red[2] + s_red[3];
        __syncthreads();
        if (ctot >= NCAND_MIN) lo = mid; else hi = mid - 1;
    }
    int T = lo;

    if (t == 0) s_cnt = 0;
    __syncthreads();
    #pragma unroll
    for (int k = 0; k < 48; ++k) {
        if ((int)u[k] >= T) {
            unsigned pos = atomicAdd(&s_cnt, 1u);
            if (pos < CMAX) candi[pos] = 16 * (t + 256 * (k >> 4)) + (k & 15);
        }
    }
    __syncthreads();
    int c = (int)s_cnt; if (c > CMAX) c = CMAX;

    // fp64 recompute of candidate dots
    if (t < c) {
        const double* xc = xn64 + (size_t)candi[t] * D;
        double acc = 0.0;
        #pragma unroll 8
        for (int k = 0; k < D; ++k) acc += s_xr[k] * xc[k];
        candv[t] = acc;
    }
    __syncthreads();

    // rank-by-count: exact fp64 top-31, ties -> lower index
    int   sel_idx = -1;
    float sel_val = 0.f;
    if (t < c) {
        double v = candv[t];
        int    id = candi[t];
        int rank = 0;
        for (int j = 0; j < c; ++j) {
            double vj = candv[j];
            rank += (vj > v || (vj == v && candi[j] < id)) ? 1 : 0;
        }
        if (rank < K_TOP) {
            sel_idx = id;
            sel_val = (v > 0.0) ? (float)v : 0.f;
        }
    }

    // write zeros (nontemporal), then scatter selected (barrier orders WAW)
    float4_e* Orow4 = (float4_e*)(Cout + (size_t)r * N_ITEMS);
    float4_e z = {0.f, 0.f, 0.f, 0.f};
    #pragma unroll
    for (int j = 0; j < 12; ++j)
        __builtin_nontemporal_store(z, &Orow4[t + 256 * j]);
    __syncthreads();
    if (sel_idx >= 0) Cout[(size_t)r * N_ITEMS + sel_idx] = sel_val;
}

// ---------------------------------------------------------------------------
extern "C" void kernel_launch(void* const* d_in, const int* in_sizes, int n_in,
                              void* d_out, int out_size, void* d_ws, size_t ws_size,
                              hipStream_t stream) {
    const float* user_emb = (const float*)d_in[0];
    const float* item_emb = (const float*)d_in[1];
    const int*   edge_row = (const int*)d_in[2];
    const int*   edge_col = (const int*)d_in[3];
    const float* edge_val = (const float*)d_in[4];
    float* C = (float*)d_out;

    double* e1d  = (double*)d_ws;                         // N_NODES*D
    double* xn64 = e1d + (size_t)N_NODES * D;             // N_ITEMS*D
    int2*   ep   = (int2*)(xn64 + (size_t)N_ITEMS * D);   // NNZ int2
    ushort* xh   = (ushort*)(ep + NNZ);                   // N_ITEMS*D bf16
    unsigned char* Cu8 = (unsigned char*)(xh + (size_t)N_ITEMS * D);  // 151 MB
    int*  cnt       = (int*)(Cu8 + (size_t)N_ITEMS * N_ITEMS);
    int*  excl      = cnt + N_NODES;
    int*  row_start = excl + N_NODES;
    int*  cursor    = row_start + N_NODES + 1;
    int*  bsum      = cursor + N_NODES;

    (void)hipMemsetAsync(cnt, 0, N_NODES * sizeof(int), stream);

    count_kernel<<<NNZ / 256, 256, 0, stream>>>(edge_row, cnt);
    scanA_kernel<<<N_NODES / 256, 256, 0, stream>>>(cnt, excl, bsum);
    scanC_kernel<<<N_NODES / 256, 256, 0, stream>>>(excl, bsum, row_start, cursor);
    scatter_kernel<<<NNZ / 256, 256, 0, stream>>>(edge_row, edge_col, edge_val, cursor, ep);

    spmm_csr_kernel<<<N_NODES / 4, 256, 0, stream>>>(row_start, ep, user_emb, item_emb, e1d);
    spmm_norm_kernel<<<N_ITEMS / 4, 256, 0, stream>>>(row_start, ep, item_emb, e1d, xn64, xh);

    dim3 ggrid(N_ITEMS / 128, N_ITEMS / 128);
    simgemm_kernel<<<ggrid, 256, 0, stream>>>(xh, Cu8);

    topk_kernel<<<N_ITEMS, 256, 0, stream>>>(Cu8, C, xn64);
}